// Round 10
// baseline (78.683 us; speedup 1.0000x reference)
//
#include <hip/hip_runtime.h>
#include <hip/hip_fp16.h>

#define B_ 64
#define I_ 1152
#define C_ 32
#define E_ 16
#define D_ 8
#define BC_ 16               // batch rows per block (4 waves, j=4 each)
#define ICt 6                // i's per block
#define NIC (I_/ICt)         // 192 i-chunks
#define ICX (NIC/8)          // 24 i-chunks per XCD slab
#define WROW4 (C_*D_*E_/4)   // 1024 float4 per W[i]
#define SCE (B_*C_*E_)       // 32768 s-elements
#define SCE2 (SCE/2)         // 16384 half2 pairs

// async global->LDS DMA, 16B per lane (dest = wave-uniform base + lane*16)
__device__ __forceinline__ void gload_lds16(const void* g, void* l) {
  typedef __attribute__((address_space(1))) const void GV;
  typedef __attribute__((address_space(3))) void LV;
  __builtin_amdgcn_global_load_lds((GV*)g, (LV*)l, 16, 0, 0);
}

#define WAITVM(N) do { asm volatile("s_waitcnt vmcnt(" #N ")" ::: "memory"); \
                       __builtin_amdgcn_sched_barrier(0); } while (0)
#define WAITLG0()  do { asm volatile("s_waitcnt lgkmcnt(0)" ::: "memory");   \
                       __builtin_amdgcn_sched_barrier(0); } while (0)

// Recompute u_hat[b,i,c,e] = sum_d x[b,i,d]*W[i,c,d,e]; coupling coef (uniform
// or softmax_c of u_hat . vacc, no max-subtraction: logits bounded, f32 exp
// safe); accumulate partial s (f16-packed) over the block's i-chunk.
// 256 thr: c=t&31, eh=(t>>5)&1, bq=t>>6, j=0..3 -> b = b0 + bq*4 + j.
// j=4 so each W LDS read feeds 4 batch rows (halves LDS-read cycles vs j=2,
// which round-9 analysis showed was the caps_pass bound at ~11.5 us/pass).
// W staged via global_load_lds into a 3-buffer, 2-deep pipeline with counted
// vmcnt + raw barriers (T3/T4): per-period wait targets W(p) issued TWO
// periods earlier, so W(p+1),W(p+2) stay in flight across barriers.
// Grid = 192 ic x 4 b-slabs = 768 blocks = EXACTLY 3 resident blocks/CU.
// Swizzle (quad rotated by c-row) on the GLOBAL source address (rule 21).
// Block map (XCD slab, perf-only): xcd=bid&7 -> ic slab; slab W (2.36MB)
// stays L2-resident across its 4 b-slabs.
template<bool ROUTE>
__global__ __launch_bounds__(256)
void caps_pass(const float* __restrict__ x, const float* __restrict__ W,
               const float* __restrict__ vacc, __half* __restrict__ partial)
{
  __shared__ float4 Wl[3][C_*32];     // 3 x 16KB W buffers
  __shared__ float4 xl[BC_*ICt*2];    // 192 float4 (3KB)

  const int t   = threadIdx.x;
  const int c   = t & 31;
  const int eh  = (t >> 5) & 1;
  const int bq  = t >> 6;
  const int xcd = blockIdx.x & 7;
  const int sl  = blockIdx.x >> 3;    // 0..95
  const int ic  = xcd * ICX + (sl >> 2);
  const int b0  = (sl & 3) * BC_;
  const int i0  = ic * ICt;

  // DMA staging map: LDS linear float4 index g = t + 256k; row cc = g>>5,
  // slot = g&31 = c. Want Wl[cc*32 + ((q+cc)&31)] = wg[cc*32+q]
  // => src quad f = cc*32 + ((c - cc)&31).
  int fsrc[4];
#pragma unroll
  for (int k = 0; k < 4; ++k) {
    int cc = (t >> 5) + 8*k;
    fsrc[k] = cc*32 + ((c - cc) & 31);
  }

  float vr[4][8];
  if (ROUTE) {
#pragma unroll
    for (int j = 0; j < 4; ++j) {
      const float4* vp = (const float4*)(vacc + (((size_t)(b0 + bq*4 + j)*C_ + c)*E_ + eh*8));
      float4 a = vp[0], b = vp[1];
      vr[j][0]=a.x; vr[j][1]=a.y; vr[j][2]=a.z; vr[j][3]=a.w;
      vr[j][4]=b.x; vr[j][5]=b.y; vr[j][6]=b.z; vr[j][7]=b.w;
    }
  }

  // stage x for all ICt i's (192 float4: 16 b x 12)
  if (t < BC_*ICt*2) {
    int b = t / (ICt*2), r = t % (ICt*2);
    xl[t] = ((const float4*)x)[ ((size_t)(b0 + b)*I_ + i0)*2 + r ];
  }

  const float4* wg = (const float4*)(W + (size_t)i0 * (C_*D_*E_));
  // prologue: issue W[i0]->buf0 and W[i0+1]->buf1 (stay in flight)
#pragma unroll
  for (int k = 0; k < 4; ++k) gload_lds16(wg + fsrc[k],          &Wl[0][t + 256*k]);
#pragma unroll
  for (int k = 0; k < 4; ++k) gload_lds16(wg + WROW4 + fsrc[k],  &Wl[1][t + 256*k]);

  float acc[4][8];
#pragma unroll
  for (int j = 0; j < 4; ++j)
#pragma unroll
    for (int e = 0; e < 8; ++e) acc[j][e] = 0.f;

  int cur = 0;
  for (int ii = 0; ii < ICt; ++ii) {
    // barrier 1: all waves done READING the buffer DMA(ii+2) will overwrite
    // (and, at ii=0, xl ds_writes drained)
    WAITLG0();
    __builtin_amdgcn_s_barrier();
    __builtin_amdgcn_sched_barrier(0);

    if (ii + 2 < ICt) {                          // issue 2-ahead prefetch
      int pre = cur + 2; if (pre >= 3) pre -= 3;
      const float4* wn = wg + (size_t)(ii + 2) * WROW4;
#pragma unroll
      for (int k = 0; k < 4; ++k)
        gload_lds16(wn + fsrc[k], &Wl[pre][t + 256*k]);
    }

    // wait for OWN W(ii) batch (leaves W(ii+1),W(ii+2) in flight), then
    // barrier 2: every wave's W(ii) quarter has landed.
    if (ii < ICt - 2)       WAITVM(8);
    else if (ii == ICt - 2) WAITVM(4);
    else                    WAITVM(0);
    __builtin_amdgcn_s_barrier();
    __builtin_amdgcn_sched_barrier(0);

    float xv[4][8];
#pragma unroll
    for (int j = 0; j < 4; ++j) {
      float4 a = xl[(bq*4 + j)*(ICt*2) + ii*2 + 0];
      float4 b = xl[(bq*4 + j)*(ICt*2) + ii*2 + 1];
      xv[j][0]=a.x; xv[j][1]=a.y; xv[j][2]=a.z; xv[j][3]=a.w;
      xv[j][4]=b.x; xv[j][5]=b.y; xv[j][6]=b.z; xv[j][7]=b.w;
    }

    float uh[4][8];
#pragma unroll
    for (int j = 0; j < 4; ++j)
#pragma unroll
      for (int e = 0; e < 8; ++e) uh[j][e] = 0.f;

#pragma unroll
    for (int d = 0; d < D_; ++d) {
#pragma unroll
      for (int qq = 0; qq < 2; ++qq) {
        float4 wv = Wl[cur][c*32 + (((d*4 + eh*2 + qq) + c) & 31)];
        const int eb = qq*4;
#pragma unroll
        for (int j = 0; j < 4; ++j) {
          uh[j][eb+0] = fmaf(xv[j][d], wv.x, uh[j][eb+0]);
          uh[j][eb+1] = fmaf(xv[j][d], wv.y, uh[j][eb+1]);
          uh[j][eb+2] = fmaf(xv[j][d], wv.z, uh[j][eb+2]);
          uh[j][eb+3] = fmaf(xv[j][d], wv.w, uh[j][eb+3]);
        }
      }
    }

    float coef[4];
    if (ROUTE) {
#pragma unroll
      for (int j = 0; j < 4; ++j) {
        float lg = 0.f;
#pragma unroll
        for (int e = 0; e < 8; ++e) lg = fmaf(uh[j][e], vr[j][e], lg);
        lg += __shfl_xor(lg, 32, 64);            // combine e-halves
        float p = __expf(lg);                    // no max-sub: |lg| bounded
        float s = p;
#pragma unroll
        for (int mk = 16; mk >= 1; mk >>= 1) s += __shfl_xor(s, mk, 64);
        coef[j] = p * __builtin_amdgcn_rcpf(s);
      }
    } else {
#pragma unroll
      for (int j = 0; j < 4; ++j) coef[j] = (1.0f / C_);
    }

#pragma unroll
    for (int j = 0; j < 4; ++j)
#pragma unroll
      for (int e = 0; e < 8; ++e) acc[j][e] = fmaf(coef[j], uh[j][e], acc[j][e]);

    cur = (cur + 1 == 3) ? 0 : cur + 1;
  }

  // partial s (f16) for this i-chunk: [NIC][B][C][E] halfs, 16B/j store
#pragma unroll
  for (int j = 0; j < 4; ++j) {
    size_t base = ((size_t)ic * B_ + (b0 + bq*4 + j)) * (C_*E_) + (size_t)c*E_ + eh*8;
    __half2 h0 = __float22half2_rn({acc[j][0], acc[j][1]});
    __half2 h1 = __float22half2_rn({acc[j][2], acc[j][3]});
    __half2 h2 = __float22half2_rn({acc[j][4], acc[j][5]});
    __half2 h3 = __float22half2_rn({acc[j][6], acc[j][7]});
    __half2* dst = (__half2*)(partial + base);
    dst[0] = h0; dst[1] = h1; dst[2] = h2; dst[3] = h3;   // contiguous 16B
  }
}

// Fused reduce+squash on f16 partial: grid 256 blocks x 256 thr. Block covers
// 64 half2 pairs (128 cells); thread (pair = bid*64 + (t&63), part = t>>6)
// sums 48 chunks as float2; LDS combine of 4 parts; squash over e (16 cells =
// 8 pairs = 8-lane shfl group). mode 0: vacc = v ; 1: vacc += v ; 2: out = v
__global__ __launch_bounds__(256)
void reduce_squash(const __half2* __restrict__ partial, float* __restrict__ vacc,
                   float* __restrict__ out, int mode)
{
  __shared__ float2 sm[256];
  const int t    = threadIdx.x;
  const int pair = blockIdx.x*64 + (t & 63);
  const int part = t >> 6;
  const __half2* p = partial + (size_t)(part*(NIC/4)) * SCE2 + pair;
  float2 s = {0.f, 0.f};
#pragma unroll 8
  for (int k = 0; k < NIC/4; ++k) {
    float2 f = __half22float2(p[(size_t)k * SCE2]);
    s.x += f.x; s.y += f.y;
  }
  sm[t] = s;
  __syncthreads();
  if (t < 64) {
    float2 a = sm[t], b = sm[t+64], c2 = sm[t+128], d = sm[t+192];
    float2 tot = {a.x+b.x+c2.x+d.x, a.y+b.y+c2.y+d.y};
    float sq = tot.x*tot.x + tot.y*tot.y;
    sq += __shfl_xor(sq, 1); sq += __shfl_xor(sq, 2); sq += __shfl_xor(sq, 4);
    float scale = sq / (1.f + sq) / (sqrtf(sq) + 1e-8f);
    float vx = scale * tot.x, vy = scale * tot.y;
    const int cell = pair * 2;
    if (mode == 0)      { vacc[cell] = vx;  vacc[cell+1] = vy;  }
    else if (mode == 1) { vacc[cell] += vx; vacc[cell+1] += vy; }
    else                { out[cell]  = vx;  out[cell+1]  = vy;  }
  }
}

extern "C" void kernel_launch(void* const* d_in, const int* in_sizes, int n_in,
                              void* d_out, int out_size, void* d_ws, size_t ws_size,
                              hipStream_t stream)
{
  const float* x = (const float*)d_in[0];
  const float* W = (const float*)d_in[1];
  float* out     = (float*)d_out;

  __half* partial = (__half*)d_ws;                          // NIC*SCE halfs = 12.6 MB
  float*  vacc    = (float*)((char*)d_ws + (size_t)NIC*SCE*sizeof(__half));

  dim3 pg(NIC * (B_/BC_));                                  // 768 blocks (3/CU exact)
  const int rg = SCE2 / 64;                                 // 256 blocks

  // iter 0: uniform coefficients (softmax of zeros = 1/32)
  caps_pass<false><<<pg, 256, 0, stream>>>(x, W, nullptr, partial);
  reduce_squash<<<rg, 256, 0, stream>>>((const __half2*)partial, vacc, nullptr, 0);
  // iter 1: logits = u_hat . v0
  caps_pass<true ><<<pg, 256, 0, stream>>>(x, W, vacc, partial);
  reduce_squash<<<rg, 256, 0, stream>>>((const __half2*)partial, vacc, nullptr, 1);
  // iter 2: logits = u_hat . (v0+v1)
  caps_pass<true ><<<pg, 256, 0, stream>>>(x, W, vacc, partial);
  reduce_squash<<<rg, 256, 0, stream>>>((const __half2*)partial, vacc, out, 2);
}

// Round 11
// 73.871 us; speedup vs baseline: 1.0651x; 1.0651x over previous
//
#include <hip/hip_runtime.h>
#include <hip/hip_fp16.h>

#define B_ 64
#define I_ 1152
#define C_ 32
#define E_ 16
#define D_ 8
#define BC_ 8                // batch rows per block (4 waves, j=2 each)
#define ICt 12               // i's per block
#define NIC (I_/ICt)         // 96 i-chunks
#define ICX (NIC/8)          // 12 i-chunks per XCD slab
#define SCE (B_*C_*E_)       // 32768 s-elements
#define SCE2 (SCE/2)         // 16384 half2 pairs
#define WIB 8192             // bytes per W[i] in f16 (32c x 16 granules x 16B)

// async global->LDS DMA, 16B per lane (dest = wave-uniform base + lane*16)
__device__ __forceinline__ void gload_lds16(const void* g, void* l) {
  typedef __attribute__((address_space(1))) const void GV;
  typedef __attribute__((address_space(3))) void LV;
  __builtin_amdgcn_global_load_lds((GV*)g, (LV*)l, 16, 0, 0);
}

#define WAITVM4() do { asm volatile("s_waitcnt vmcnt(4)" ::: "memory"); \
                       __builtin_amdgcn_sched_barrier(0); } while (0)
#define WAITVM2() do { asm volatile("s_waitcnt vmcnt(2)" ::: "memory"); \
                       __builtin_amdgcn_sched_barrier(0); } while (0)
#define WAITVM0() do { asm volatile("s_waitcnt vmcnt(0)" ::: "memory"); \
                       __builtin_amdgcn_sched_barrier(0); } while (0)
#define WAITLG0() do { asm volatile("s_waitcnt lgkmcnt(0)" ::: "memory"); \
                       __builtin_amdgcn_sched_barrier(0); } while (0)

typedef _Float16 h2v __attribute__((ext_vector_type(2)));

__device__ __forceinline__ float dot2f(__half2 a, __half2 b, float c) {
#if defined(__has_builtin)
#if __has_builtin(__builtin_amdgcn_fdot2)
  return __builtin_amdgcn_fdot2(__builtin_bit_cast(h2v, a),
                                __builtin_bit_cast(h2v, b), c, false);
#else
  float2 fa = __half22float2(a), fb = __half22float2(b);
  return fmaf(fa.x, fb.x, fmaf(fa.y, fb.y, c));
#endif
#else
  float2 fa = __half22float2(a), fb = __half22float2(b);
  return fmaf(fa.x, fb.x, fmaf(fa.y, fb.y, c));
#endif
}

// One-time convert: W -> f16 granules [i][c][q] (q = d*2+eh, 16B each),
// x -> duplicated half2 [b][i][d] (for v_pk_fma broadcast operand).
__global__ __launch_bounds__(256)
void convert_wx(const float* __restrict__ W, const float* __restrict__ x,
                __half* __restrict__ Wh, __half2* __restrict__ xh)
{
  const int bid = blockIdx.x;
  const int t   = threadIdx.x;
  if (bid < 2304) {                       // W: one granule per thread
    int G = bid*256 + t;                  // 0..589823 = [i][c][q]
    const float4* src = (const float4*)(W + (size_t)G*8);
    float4 a = src[0], b = src[1];
    __half2 h0 = __float22half2_rn({a.x, a.y});
    __half2 h1 = __float22half2_rn({a.z, a.w});
    __half2 h2 = __float22half2_rn({b.x, b.y});
    __half2 h3 = __float22half2_rn({b.z, b.w});
    float4 o;
    o.x = __builtin_bit_cast(float, h0); o.y = __builtin_bit_cast(float, h1);
    o.z = __builtin_bit_cast(float, h2); o.w = __builtin_bit_cast(float, h3);
    *(float4*)(Wh + (size_t)G*8) = o;
  } else {                                // x: 4 dup-half2 per thread
    int k = (bid - 2304)*256 + t;         // 0..147455
    const float4* src = (const float4*)(x + (size_t)k*4);
    float4 a = src[0];
    float4 o;
    o.x = __builtin_bit_cast(float, __float22half2_rn({a.x, a.x}));
    o.y = __builtin_bit_cast(float, __float22half2_rn({a.y, a.y}));
    o.z = __builtin_bit_cast(float, __float22half2_rn({a.z, a.z}));
    o.w = __builtin_bit_cast(float, __float22half2_rn({a.w, a.w}));
    *(float4*)(xh + (size_t)k*4) = o;
  }
}

// Recompute u_hat in packed f16 (v_pk_fma_f16): uh[e-pair] += x_dup * W_pair.
// Coupling coef via softmax_c of dot2(uh, v) (no max-sub; logits bounded).
// 256 thr: c=t&31, eh=(t>>5)&1, bq=t>>6, j=0..1 -> b = b0 + bq*2 + j.
// W f16 staged via global_load_lds, 3-buffer 2-deep counted-vmcnt pipeline
// (2 DMA/period -> ladder 4/2/0). LDS granule swizzle q^(c&15) applied on the
// GLOBAL source (rule 21); read at the b128 bandwidth floor (2 lanes/granule).
// Grid = 96 ic x 8 b-slabs = 768 blocks = exactly 3 resident blocks/CU.
// XCD slab map (perf-only): xcd=bid&7 -> 12-ic slab; slab Wh (1.18MB) L2-hot.
template<bool ROUTE>
__global__ __launch_bounds__(256)
void caps_pass(const __half2* __restrict__ xh, const char* __restrict__ Wh,
               const float* __restrict__ vacc, __half* __restrict__ partial)
{
  __shared__ float4 Wl[3][512];       // 3 x 8KB f16 W buffers
  __shared__ __half2 xl[BC_*ICt*D_];  // 768 half2 (3KB)

  const int t   = threadIdx.x;
  const int c   = t & 31;
  const int eh  = (t >> 5) & 1;
  const int bq  = t >> 6;
  const int xcd = blockIdx.x & 7;
  const int sl  = blockIdx.x >> 3;    // 0..95
  const int ic  = xcd * ICX + (sl >> 3);
  const int b0  = (sl & 7) * BC_;
  const int i0  = ic * ICt;

  // DMA staging: LDS granule g = t + 256k; row cc = g>>4, slot q = g&15;
  // source granule = q ^ (cc&15)  (read side applies the same XOR).
  int fsrc[2];
#pragma unroll
  for (int k = 0; k < 2; ++k) {
    int g = t + 256*k, cc = g >> 4, q = g & 15;
    fsrc[k] = cc*256 + ((q ^ (cc & 15)) << 4);    // byte offset in Wh[i]
  }

  __half2 vrp[2][4];
  if (ROUTE) {
#pragma unroll
    for (int j = 0; j < 2; ++j) {
      const float4* vp = (const float4*)(vacc + (((size_t)(b0 + bq*2 + j)*C_ + c)*E_ + eh*8));
      float4 a = vp[0], b = vp[1];
      vrp[j][0] = __float22half2_rn({a.x, a.y});
      vrp[j][1] = __float22half2_rn({a.z, a.w});
      vrp[j][2] = __float22half2_rn({b.x, b.y});
      vrp[j][3] = __float22half2_rn({b.z, b.w});
    }
  }

  // stage x: 8 b x 12 i x 8 d dup-half2 = 384B/b; t<192 stage 16B each
  if (t < BC_*ICt*D_/4) {
    int b = t / 24, r = t % 24;
    float4 v = ((const float4*)(xh + ((size_t)(b0 + b)*I_ + i0)*D_))[r];
    ((float4*)xl)[b*24 + r] = v;
  }

  const char* wg = Wh + (size_t)i0 * WIB;
  // prologue: W[i0]->buf0, W[i0+1]->buf1 (4 loads in flight)
#pragma unroll
  for (int k = 0; k < 2; ++k) gload_lds16(wg + fsrc[k],        (char*)&Wl[0][0] + (t + 256*k)*16);
#pragma unroll
  for (int k = 0; k < 2; ++k) gload_lds16(wg + WIB + fsrc[k],  (char*)&Wl[1][0] + (t + 256*k)*16);

  __half2 accp[2][4];
#pragma unroll
  for (int j = 0; j < 2; ++j)
#pragma unroll
    for (int q = 0; q < 4; ++q) accp[j][q] = __half2{__half(0.f), __half(0.f)};

  int cur = 0;
  for (int ii = 0; ii < ICt; ++ii) {
    // barrier 1: all waves done reading the buffer DMA(ii+2) overwrites
    // (and, at ii=0, xl ds_writes drained)
    WAITLG0();
    __builtin_amdgcn_s_barrier();
    __builtin_amdgcn_sched_barrier(0);

    if (ii + 2 < ICt) {                          // 2-ahead prefetch
      int pre = cur + 2; if (pre >= 3) pre -= 3;
      const char* wn = wg + (size_t)(ii + 2) * WIB;
#pragma unroll
      for (int k = 0; k < 2; ++k)
        gload_lds16(wn + fsrc[k], (char*)&Wl[pre][0] + (t + 256*k)*16);
    }

    // wait for OWN W(ii) pair (W(ii+1),W(ii+2) stay in flight), then
    // barrier 2: every wave's W(ii) slice landed.
    if (ii < ICt - 2)       WAITVM4();
    else if (ii == ICt - 2) WAITVM2();
    else                    WAITVM0();
    __builtin_amdgcn_s_barrier();
    __builtin_amdgcn_sched_barrier(0);

    __half2 uhp[2][4];
#pragma unroll
    for (int j = 0; j < 2; ++j)
#pragma unroll
      for (int q = 0; q < 4; ++q) uhp[j][q] = __half2{__half(0.f), __half(0.f)};

    const char* wrow = (const char*)&Wl[cur][0] + c*256;
    const __half2* xr0 = xl + (bq*2 + 0)*(ICt*D_) + ii*D_;
    const __half2* xr1 = xl + (bq*2 + 1)*(ICt*D_) + ii*D_;
#pragma unroll
    for (int d = 0; d < D_; ++d) {
      float4 w4 = *(const float4*)(wrow + ((((d*2 + eh) ^ (c & 15))) << 4));
      __half2 w0 = __builtin_bit_cast(__half2, w4.x);
      __half2 w1 = __builtin_bit_cast(__half2, w4.y);
      __half2 w2 = __builtin_bit_cast(__half2, w4.z);
      __half2 w3 = __builtin_bit_cast(__half2, w4.w);
      __half2 x0 = xr0[d], x1 = xr1[d];
      uhp[0][0] = __hfma2(x0, w0, uhp[0][0]);
      uhp[0][1] = __hfma2(x0, w1, uhp[0][1]);
      uhp[0][2] = __hfma2(x0, w2, uhp[0][2]);
      uhp[0][3] = __hfma2(x0, w3, uhp[0][3]);
      uhp[1][0] = __hfma2(x1, w0, uhp[1][0]);
      uhp[1][1] = __hfma2(x1, w1, uhp[1][1]);
      uhp[1][2] = __hfma2(x1, w2, uhp[1][2]);
      uhp[1][3] = __hfma2(x1, w3, uhp[1][3]);
    }

    float coef[2];
    if (ROUTE) {
#pragma unroll
      for (int j = 0; j < 2; ++j) {
        float lg = 0.f;
#pragma unroll
        for (int q = 0; q < 4; ++q) lg = dot2f(uhp[j][q], vrp[j][q], lg);
        lg += __shfl_xor(lg, 32, 64);            // combine e-halves
        float p = __expf(lg);                    // no max-sub: |lg| bounded
        float s = p;
#pragma unroll
        for (int mk = 16; mk >= 1; mk >>= 1) s += __shfl_xor(s, mk, 64);
        coef[j] = p * __builtin_amdgcn_rcpf(s);
      }
    } else {
#pragma unroll
      for (int j = 0; j < 2; ++j) coef[j] = (1.0f / C_);
    }

#pragma unroll
    for (int j = 0; j < 2; ++j) {
      __half2 cp = __float2half2_rn(coef[j]);
#pragma unroll
      for (int q = 0; q < 4; ++q) accp[j][q] = __hfma2(cp, uhp[j][q], accp[j][q]);
    }

    cur = (cur + 1 == 3) ? 0 : cur + 1;
  }

  // partial s (f16) for this i-chunk: [NIC][B][C][E], 16B store per j
#pragma unroll
  for (int j = 0; j < 2; ++j) {
    size_t base = ((size_t)ic * B_ + (b0 + bq*2 + j)) * (C_*E_) + (size_t)c*E_ + eh*8;
    float4 o;
    o.x = __builtin_bit_cast(float, accp[j][0]);
    o.y = __builtin_bit_cast(float, accp[j][1]);
    o.z = __builtin_bit_cast(float, accp[j][2]);
    o.w = __builtin_bit_cast(float, accp[j][3]);
    *(float4*)(partial + base) = o;
  }
}

// Fused reduce+squash on f16 partial: 256 blocks x 256 thr. Block covers 64
// half2 pairs (128 cells); thread (pair, part=t>>6) sums 24 chunks as float2;
// LDS combine of 4 parts; squash over e (8-pair shfl group).
// mode 0: vacc = v ; 1: vacc += v ; 2: out = v
__global__ __launch_bounds__(256)
void reduce_squash(const __half2* __restrict__ partial, float* __restrict__ vacc,
                   float* __restrict__ out, int mode)
{
  __shared__ float2 sm[256];
  const int t    = threadIdx.x;
  const int pair = blockIdx.x*64 + (t & 63);
  const int part = t >> 6;
  const __half2* p = partial + (size_t)(part*(NIC/4)) * SCE2 + pair;
  float2 s = {0.f, 0.f};
#pragma unroll 6
  for (int k = 0; k < NIC/4; ++k) {
    float2 f = __half22float2(p[(size_t)k * SCE2]);
    s.x += f.x; s.y += f.y;
  }
  sm[t] = s;
  __syncthreads();
  if (t < 64) {
    float2 a = sm[t], b = sm[t+64], c2 = sm[t+128], d = sm[t+192];
    float2 tot = {a.x+b.x+c2.x+d.x, a.y+b.y+c2.y+d.y};
    float sq = tot.x*tot.x + tot.y*tot.y;
    sq += __shfl_xor(sq, 1); sq += __shfl_xor(sq, 2); sq += __shfl_xor(sq, 4);
    float scale = sq / (1.f + sq) / (sqrtf(sq) + 1e-8f);
    float vx = scale * tot.x, vy = scale * tot.y;
    const int cell = pair * 2;
    if (mode == 0)      { vacc[cell] = vx;  vacc[cell+1] = vy;  }
    else if (mode == 1) { vacc[cell] += vx; vacc[cell+1] += vy; }
    else                { out[cell]  = vx;  out[cell+1]  = vy;  }
  }
}

extern "C" void kernel_launch(void* const* d_in, const int* in_sizes, int n_in,
                              void* d_out, int out_size, void* d_ws, size_t ws_size,
                              hipStream_t stream)
{
  const float* x = (const float*)d_in[0];
  const float* W = (const float*)d_in[1];
  float* out     = (float*)d_out;

  char* ws = (char*)d_ws;
  __half*  partial = (__half*)ws;                    ws += (size_t)NIC*SCE*2;   // 6.3 MB
  float*   vacc    = (float*)ws;                     ws += (size_t)SCE*4;       // 128 KB
  __half*  Wh      = (__half*)ws;                    ws += (size_t)I_*C_*D_*E_*2; // 9.4 MB
  __half2* xh      = (__half2*)ws;                                             // 2.36 MB

  dim3 pg(NIC * (B_/BC_));                           // 768 blocks (3/CU exact)
  const int rg = SCE2 / 64;                          // 256 blocks

  convert_wx<<<2880, 256, 0, stream>>>(W, x, Wh, xh);

  // iter 0: uniform coefficients (softmax of zeros = 1/32)
  caps_pass<false><<<pg, 256, 0, stream>>>(xh, (const char*)Wh, nullptr, partial);
  reduce_squash<<<rg, 256, 0, stream>>>((const __half2*)partial, vacc, nullptr, 0);
  // iter 1: logits = u_hat . v0
  caps_pass<true ><<<pg, 256, 0, stream>>>(xh, (const char*)Wh, vacc, partial);
  reduce_squash<<<rg, 256, 0, stream>>>((const __half2*)partial, vacc, nullptr, 1);
  // iter 2: logits = u_hat . (v0+v1)
  caps_pass<true ><<<pg, 256, 0, stream>>>(xh, (const char*)Wh, vacc, partial);
  reduce_squash<<<rg, 256, 0, stream>>>((const __half2*)partial, vacc, out, 2);
}

// Round 12
// 73.552 us; speedup vs baseline: 1.0698x; 1.0043x over previous
//
#include <hip/hip_runtime.h>
#include <hip/hip_fp16.h>

#define B_ 64
#define I_ 1152
#define C_ 32
#define E_ 16
#define D_ 8
#define BC_ 8                // batch rows per block (4 waves, j=2 each)
#define ICt 12               // i's per block (6 periods x 2 i)
#define NIC (I_/ICt)         // 96 i-chunks
#define ICX (NIC/8)          // 12 i-chunks per XCD slab
#define SCE (B_*C_*E_)       // 32768 s-elements
#define SCE2 (SCE/2)         // 16384 half2 pairs
#define WIB 8192             // bytes per W[i] in f16 (32c x 16 granules x 16B)

// async global->LDS DMA, 16B per lane (dest = wave-uniform base + lane*16)
__device__ __forceinline__ void gload_lds16(const void* g, void* l) {
  typedef __attribute__((address_space(1))) const void GV;
  typedef __attribute__((address_space(3))) void LV;
  __builtin_amdgcn_global_load_lds((GV*)g, (LV*)l, 16, 0, 0);
}

#define WAITVM8() do { asm volatile("s_waitcnt vmcnt(8)" ::: "memory"); \
                       __builtin_amdgcn_sched_barrier(0); } while (0)
#define WAITVM4() do { asm volatile("s_waitcnt vmcnt(4)" ::: "memory"); \
                       __builtin_amdgcn_sched_barrier(0); } while (0)
#define WAITVM0() do { asm volatile("s_waitcnt vmcnt(0)" ::: "memory"); \
                       __builtin_amdgcn_sched_barrier(0); } while (0)
#define WAITLG0() do { asm volatile("s_waitcnt lgkmcnt(0)" ::: "memory"); \
                       __builtin_amdgcn_sched_barrier(0); } while (0)

typedef _Float16 h2v __attribute__((ext_vector_type(2)));

__device__ __forceinline__ float dot2f(__half2 a, __half2 b, float c) {
#if defined(__has_builtin)
#if __has_builtin(__builtin_amdgcn_fdot2)
  return __builtin_amdgcn_fdot2(__builtin_bit_cast(h2v, a),
                                __builtin_bit_cast(h2v, b), c, false);
#else
  float2 fa = __half22float2(a), fb = __half22float2(b);
  return fmaf(fa.x, fb.x, fmaf(fa.y, fb.y, c));
#endif
#else
  float2 fa = __half22float2(a), fb = __half22float2(b);
  return fmaf(fa.x, fb.x, fmaf(fa.y, fb.y, c));
#endif
}

// One-time convert: W -> f16 granules [i][c][q] (q = d*2+eh, 16B each),
// x -> duplicated half2 [b][i][d] (broadcast operand for v_pk_fma_f16).
__global__ __launch_bounds__(256)
void convert_wx(const float* __restrict__ W, const float* __restrict__ x,
                __half* __restrict__ Wh, __half2* __restrict__ xh)
{
  const int bid = blockIdx.x;
  const int t   = threadIdx.x;
  if (bid < 2304) {                       // W: one granule per thread
    int G = bid*256 + t;                  // 0..589823 = [i][c][q]
    const float4* src = (const float4*)(W + (size_t)G*8);
    float4 a = src[0], b = src[1];
    __half2 h0 = __float22half2_rn({a.x, a.y});
    __half2 h1 = __float22half2_rn({a.z, a.w});
    __half2 h2 = __float22half2_rn({b.x, b.y});
    __half2 h3 = __float22half2_rn({b.z, b.w});
    float4 o;
    o.x = __builtin_bit_cast(float, h0); o.y = __builtin_bit_cast(float, h1);
    o.z = __builtin_bit_cast(float, h2); o.w = __builtin_bit_cast(float, h3);
    *(float4*)(Wh + (size_t)G*8) = o;
  } else {                                // x: 4 dup-half2 per thread
    int k = (bid - 2304)*256 + t;         // 0..147455
    const float4* src = (const float4*)(x + (size_t)k*4);
    float4 a = src[0];
    float4 o;
    o.x = __builtin_bit_cast(float, __float22half2_rn({a.x, a.x}));
    o.y = __builtin_bit_cast(float, __float22half2_rn({a.y, a.y}));
    o.z = __builtin_bit_cast(float, __float22half2_rn({a.z, a.z}));
    o.w = __builtin_bit_cast(float, __float22half2_rn({a.w, a.w}));
    *(float4*)(xh + (size_t)k*4) = o;
  }
}

// Packed-f16 u_hat recompute + routing softmax + partial-s accumulate.
// 256 thr: c=t&31, eh=(t>>5)&1, bq=t>>6, j=0..1 -> b = b0 + bq*2 + j.
// PER=2: each period computes TWO i's between one barrier pair -> 12
// barrier+waitcnt events/pass instead of 24; the two softmax chains are
// independent (ILP). W staged via global_load_lds into 3 x 16KB 2-i buffers,
// 2-period-deep counted-vmcnt pipeline (4 loads/period, ladder 8/4/0).
// x read from LDS as wave-uniform broadcast ds_read_b128 (4/thread/i).
// Granule swizzle q^(cc&15) applied on the GLOBAL source (rule 21).
// Grid = 96 ic x 8 b-slabs = 768 blocks = exactly 3 resident blocks/CU
// (51KB LDS). XCD slab map (perf-only): xcd=bid&7 -> 12-ic slab (1.18MB L2).
template<bool ROUTE>
__global__ __launch_bounds__(256)
void caps_pass(const __half2* __restrict__ xh, const char* __restrict__ Wh,
               const float* __restrict__ vacc, __half* __restrict__ partial)
{
  __shared__ float4 Wl[3][1024];      // 3 x 16KB buffers (2 W-i's each)
  __shared__ __half2 xl[BC_*ICt*D_];  // 768 half2 (3KB)

  const int t   = threadIdx.x;
  const int c   = t & 31;
  const int eh  = (t >> 5) & 1;
  const int bq  = t >> 6;
  const int xcd = blockIdx.x & 7;
  const int sl  = blockIdx.x >> 3;    // 0..95
  const int ic  = xcd * ICX + (sl >> 3);
  const int b0  = (sl & 7) * BC_;
  const int i0  = ic * ICt;

  // DMA staging: within-i granule g = t + 256k (k=0,1); row cc = g>>4,
  // slot q = g&15; source granule = q ^ (cc&15) (read applies same XOR).
  int fsrc[2];
#pragma unroll
  for (int k = 0; k < 2; ++k) {
    int g = t + 256*k, cc = g >> 4, q = g & 15;
    fsrc[k] = cc*256 + ((q ^ (cc & 15)) << 4);    // byte offset in Wh[i]
  }

  __half2 vrp[2][4];
  if (ROUTE) {
#pragma unroll
    for (int j = 0; j < 2; ++j) {
      const float4* vp = (const float4*)(vacc + (((size_t)(b0 + bq*2 + j)*C_ + c)*E_ + eh*8));
      float4 a = vp[0], b = vp[1];
      vrp[j][0] = __float22half2_rn({a.x, a.y});
      vrp[j][1] = __float22half2_rn({a.z, a.w});
      vrp[j][2] = __float22half2_rn({b.x, b.y});
      vrp[j][3] = __float22half2_rn({b.z, b.w});
    }
  }

  // stage x: 8 b x 12 i x 8 d dup-half2; t<192 stage one float4 each
  if (t < BC_*ICt*D_/4) {
    int b = t / 24, r = t % 24;
    float4 v = ((const float4*)(xh + ((size_t)(b0 + b)*I_ + i0)*D_))[r];
    ((float4*)xl)[b*24 + r] = v;
  }

  const char* wg = Wh + (size_t)i0 * WIB;
  // prologue: buf0 <- i0,i1 ; buf1 <- i2,i3 (8 loads in flight)
#pragma unroll
  for (int k = 0; k < 4; ++k)
    gload_lds16(wg + (k>>1)*WIB + fsrc[k&1], (char*)&Wl[0][0] + (t + 256*k)*16);
#pragma unroll
  for (int k = 0; k < 4; ++k)
    gload_lds16(wg + WIB*2 + (k>>1)*WIB + fsrc[k&1], (char*)&Wl[1][0] + (t + 256*k)*16);

  __half2 accp[2][4];
#pragma unroll
  for (int j = 0; j < 2; ++j)
#pragma unroll
    for (int q = 0; q < 4; ++q) accp[j][q] = __half2{__half(0.f), __half(0.f)};

  int cur = 0;
  for (int p = 0; p < ICt/2; ++p) {
    // barrier 1: all waves done reading the buffer DMA(p+2) overwrites
    // (and, at p=0, xl ds_writes drained)
    WAITLG0();
    __builtin_amdgcn_s_barrier();
    __builtin_amdgcn_sched_barrier(0);

    if (p + 2 < ICt/2) {                         // 2-period-ahead prefetch
      int pre = cur + 2; if (pre >= 3) pre -= 3;
      const char* wn = wg + (size_t)(p + 2) * (2*WIB);
#pragma unroll
      for (int k = 0; k < 4; ++k)
        gload_lds16(wn + (k>>1)*WIB + fsrc[k&1], (char*)&Wl[pre][0] + (t + 256*k)*16);
    }

    // wait for OWN buffer's 4-load batch (8 newer stay in flight), then
    // barrier 2: every wave's slice landed.
    if (p < ICt/2 - 2)       WAITVM8();
    else if (p == ICt/2 - 2) WAITVM4();
    else                     WAITVM0();
    __builtin_amdgcn_s_barrier();
    __builtin_amdgcn_sched_barrier(0);

#pragma unroll
    for (int il = 0; il < 2; ++il) {
      const int ii = p*2 + il;

      // x: 2 broadcast ds_read_b128 per j (wave-uniform address)
      __half2 xd0[8], xd1[8];
      {
        const float4* xr = (const float4*)xl;
        float4 a0 = xr[((bq*2 + 0)*ICt + ii)*2 + 0];
        float4 b0v = xr[((bq*2 + 0)*ICt + ii)*2 + 1];
        float4 a1 = xr[((bq*2 + 1)*ICt + ii)*2 + 0];
        float4 b1v = xr[((bq*2 + 1)*ICt + ii)*2 + 1];
        xd0[0]=__builtin_bit_cast(__half2,a0.x); xd0[1]=__builtin_bit_cast(__half2,a0.y);
        xd0[2]=__builtin_bit_cast(__half2,a0.z); xd0[3]=__builtin_bit_cast(__half2,a0.w);
        xd0[4]=__builtin_bit_cast(__half2,b0v.x); xd0[5]=__builtin_bit_cast(__half2,b0v.y);
        xd0[6]=__builtin_bit_cast(__half2,b0v.z); xd0[7]=__builtin_bit_cast(__half2,b0v.w);
        xd1[0]=__builtin_bit_cast(__half2,a1.x); xd1[1]=__builtin_bit_cast(__half2,a1.y);
        xd1[2]=__builtin_bit_cast(__half2,a1.z); xd1[3]=__builtin_bit_cast(__half2,a1.w);
        xd1[4]=__builtin_bit_cast(__half2,b1v.x); xd1[5]=__builtin_bit_cast(__half2,b1v.y);
        xd1[6]=__builtin_bit_cast(__half2,b1v.z); xd1[7]=__builtin_bit_cast(__half2,b1v.w);
      }

      __half2 uhp[2][4];
#pragma unroll
      for (int j = 0; j < 2; ++j)
#pragma unroll
        for (int q = 0; q < 4; ++q) uhp[j][q] = __half2{__half(0.f), __half(0.f)};

      const char* wrow = (const char*)&Wl[cur][0] + il*WIB + c*256;
#pragma unroll
      for (int d = 0; d < D_; ++d) {
        float4 w4 = *(const float4*)(wrow + ((((d*2 + eh) ^ (c & 15))) << 4));
        __half2 w0 = __builtin_bit_cast(__half2, w4.x);
        __half2 w1 = __builtin_bit_cast(__half2, w4.y);
        __half2 w2 = __builtin_bit_cast(__half2, w4.z);
        __half2 w3 = __builtin_bit_cast(__half2, w4.w);
        uhp[0][0] = __hfma2(xd0[d], w0, uhp[0][0]);
        uhp[0][1] = __hfma2(xd0[d], w1, uhp[0][1]);
        uhp[0][2] = __hfma2(xd0[d], w2, uhp[0][2]);
        uhp[0][3] = __hfma2(xd0[d], w3, uhp[0][3]);
        uhp[1][0] = __hfma2(xd1[d], w0, uhp[1][0]);
        uhp[1][1] = __hfma2(xd1[d], w1, uhp[1][1]);
        uhp[1][2] = __hfma2(xd1[d], w2, uhp[1][2]);
        uhp[1][3] = __hfma2(xd1[d], w3, uhp[1][3]);
      }

      float coef[2];
      if (ROUTE) {
#pragma unroll
        for (int j = 0; j < 2; ++j) {
          float lg = 0.f;
#pragma unroll
          for (int q = 0; q < 4; ++q) lg = dot2f(uhp[j][q], vrp[j][q], lg);
          lg += __shfl_xor(lg, 32, 64);          // combine e-halves
          float pexp = __expf(lg);               // no max-sub: |lg| bounded
          float s = pexp;
#pragma unroll
          for (int mk = 16; mk >= 1; mk >>= 1) s += __shfl_xor(s, mk, 64);
          coef[j] = pexp * __builtin_amdgcn_rcpf(s);
        }
      } else {
#pragma unroll
        for (int j = 0; j < 2; ++j) coef[j] = (1.0f / C_);
      }

#pragma unroll
      for (int j = 0; j < 2; ++j) {
        __half2 cp = __float2half2_rn(coef[j]);
#pragma unroll
        for (int q = 0; q < 4; ++q) accp[j][q] = __hfma2(cp, uhp[j][q], accp[j][q]);
      }
    }

    cur = (cur + 1 == 3) ? 0 : cur + 1;
  }

  // partial s (f16) for this i-chunk: [NIC][B][C][E], 16B store per j
#pragma unroll
  for (int j = 0; j < 2; ++j) {
    size_t base = ((size_t)ic * B_ + (b0 + bq*2 + j)) * (C_*E_) + (size_t)c*E_ + eh*8;
    float4 o;
    o.x = __builtin_bit_cast(float, accp[j][0]);
    o.y = __builtin_bit_cast(float, accp[j][1]);
    o.z = __builtin_bit_cast(float, accp[j][2]);
    o.w = __builtin_bit_cast(float, accp[j][3]);
    *(float4*)(partial + base) = o;
  }
}

// Fused reduce+squash on f16 partial: 512 blocks x 256 thr (2 blocks/CU).
// Block covers 32 half2 pairs (64 cells); thread (pair = bid*32 + (t&31),
// part = t>>5) sums 12 chunks as float2; LDS combine of 8 parts; squash over
// e (16 cells = 8 pairs = 8-lane shfl group).
// mode 0: vacc = v ; 1: vacc += v ; 2: out = v
__global__ __launch_bounds__(256)
void reduce_squash(const __half2* __restrict__ partial, float* __restrict__ vacc,
                   float* __restrict__ out, int mode)
{
  __shared__ float2 sm[256];
  const int t    = threadIdx.x;
  const int pair = blockIdx.x*32 + (t & 31);
  const int part = t >> 5;
  const __half2* p = partial + (size_t)(part*(NIC/8)) * SCE2 + pair;
  float2 s = {0.f, 0.f};
#pragma unroll
  for (int k = 0; k < NIC/8; ++k) {
    float2 f = __half22float2(p[(size_t)k * SCE2]);
    s.x += f.x; s.y += f.y;
  }
  sm[t] = s;
  __syncthreads();
  if (t < 32) {
    float2 tot = {0.f, 0.f};
#pragma unroll
    for (int pp = 0; pp < 8; ++pp) {
      float2 v = sm[t + 32*pp];
      tot.x += v.x; tot.y += v.y;
    }
    float sq = tot.x*tot.x + tot.y*tot.y;
    sq += __shfl_xor(sq, 1); sq += __shfl_xor(sq, 2); sq += __shfl_xor(sq, 4);
    float scale = sq / (1.f + sq) / (sqrtf(sq) + 1e-8f);
    float vx = scale * tot.x, vy = scale * tot.y;
    const int cell = pair * 2;
    if (mode == 0)      { vacc[cell] = vx;  vacc[cell+1] = vy;  }
    else if (mode == 1) { vacc[cell] += vx; vacc[cell+1] += vy; }
    else                { out[cell]  = vx;  out[cell+1]  = vy;  }
  }
}

extern "C" void kernel_launch(void* const* d_in, const int* in_sizes, int n_in,
                              void* d_out, int out_size, void* d_ws, size_t ws_size,
                              hipStream_t stream)
{
  const float* x = (const float*)d_in[0];
  const float* W = (const float*)d_in[1];
  float* out     = (float*)d_out;

  char* ws = (char*)d_ws;
  __half*  partial = (__half*)ws;                    ws += (size_t)NIC*SCE*2;     // 6.3 MB
  float*   vacc    = (float*)ws;                     ws += (size_t)SCE*4;         // 128 KB
  __half*  Wh      = (__half*)ws;                    ws += (size_t)I_*C_*D_*E_*2; // 9.4 MB
  __half2* xh      = (__half2*)ws;                                               // 2.36 MB

  dim3 pg(NIC * (B_/BC_));                           // 768 blocks (3/CU exact)
  const int rg = SCE2 / 32;                          // 512 blocks

  convert_wx<<<2880, 256, 0, stream>>>(W, x, Wh, xh);

  // iter 0: uniform coefficients (softmax of zeros = 1/32)
  caps_pass<false><<<pg, 256, 0, stream>>>(xh, (const char*)Wh, nullptr, partial);
  reduce_squash<<<rg, 256, 0, stream>>>((const __half2*)partial, vacc, nullptr, 0);
  // iter 1: logits = u_hat . v0
  caps_pass<true ><<<pg, 256, 0, stream>>>(xh, (const char*)Wh, vacc, partial);
  reduce_squash<<<rg, 256, 0, stream>>>((const __half2*)partial, vacc, nullptr, 1);
  // iter 2: logits = u_hat . (v0+v1)
  caps_pass<true ><<<pg, 256, 0, stream>>>(xh, (const char*)Wh, vacc, partial);
  reduce_squash<<<rg, 256, 0, stream>>>((const __half2*)partial, vacc, out, 2);
}

// Round 13
// 65.914 us; speedup vs baseline: 1.1937x; 1.1159x over previous
//
#include <hip/hip_runtime.h>
#include <hip/hip_fp16.h>

#define B_ 64
#define I_ 1152
#define C_ 32
#define E_ 16
#define D_ 8
#define BC_ 8                // batch rows per block (4 waves, j=2 each)
#define ICt 12               // i's per block
#define NIC (I_/ICt)         // 96 i-chunks
#define ICX (NIC/8)          // 12 i-chunks per XCD slab
#define WROW4 (C_*D_*E_/4)   // 1024 float4 per W[i] (f32)
#define SCE (B_*C_*E_)       // 32768 s-elements
#define SCE2 (SCE/2)         // 16384 half2 pairs
#define WIB 8192             // bytes per W[i] in f16 (32c x 16 granules x 16B)

// async global->LDS DMA, 16B per lane (dest = wave-uniform base + lane*16)
__device__ __forceinline__ void gload_lds16(const void* g, void* l) {
  typedef __attribute__((address_space(1))) const void GV;
  typedef __attribute__((address_space(3))) void LV;
  __builtin_amdgcn_global_load_lds((GV*)g, (LV*)l, 16, 0, 0);
}

#define WAITVM8() do { asm volatile("s_waitcnt vmcnt(8)" ::: "memory"); \
                       __builtin_amdgcn_sched_barrier(0); } while (0)
#define WAITVM4() do { asm volatile("s_waitcnt vmcnt(4)" ::: "memory"); \
                       __builtin_amdgcn_sched_barrier(0); } while (0)
#define WAITVM0() do { asm volatile("s_waitcnt vmcnt(0)" ::: "memory"); \
                       __builtin_amdgcn_sched_barrier(0); } while (0)
#define WAITLG0() do { asm volatile("s_waitcnt lgkmcnt(0)" ::: "memory"); \
                       __builtin_amdgcn_sched_barrier(0); } while (0)

typedef _Float16 h2v __attribute__((ext_vector_type(2)));

__device__ __forceinline__ float dot2f(__half2 a, __half2 b, float c) {
#if defined(__has_builtin)
#if __has_builtin(__builtin_amdgcn_fdot2)
  return __builtin_amdgcn_fdot2(__builtin_bit_cast(h2v, a),
                                __builtin_bit_cast(h2v, b), c, false);
#else
  float2 fa = __half22float2(a), fb = __half22float2(b);
  return fmaf(fa.x, fb.x, fmaf(fa.y, fb.y, c));
#endif
#else
  float2 fa = __half22float2(a), fb = __half22float2(b);
  return fmaf(fa.x, fb.x, fmaf(fa.y, fb.y, c));
#endif
}

__device__ __forceinline__ float h2bits(float a, float b) {
  return __builtin_bit_cast(float, __float22half2_rn({a, b}));
}

// ---------------- Pass 0 (f32 compute, uniform coef) + fused convert -------
// r9-proven structure: f32 W via global_load_lds, 3-buf 2-deep counted-vmcnt
// pipeline (4 loads/i, ladder 8/4/0), quad-rotate swizzle on global source.
// coef = 1/32 (softmax of zero logits). Epilogue (after partial store):
// distributed conversion for passes 1-2 -- this block converts W[i] -> f16
// granules for its chunk's i's where (ii&7)==bslab (each i converted exactly
// once grid-wide; source re-read from L2-hot global), and its own x slab
// (8 b x 12 i) -> duplicated half2 xh from the staged LDS copy.
__global__ __launch_bounds__(256)
void caps_pass0(const float* __restrict__ x, const float* __restrict__ W,
                __half* __restrict__ partial, __half* __restrict__ Wh,
                __half2* __restrict__ xh)
{
  __shared__ float4 Wl[3][1024];      // 3 x 16KB f32 W buffers
  __shared__ float4 xl[BC_*ICt*2];    // 192 float4 (3KB) f32 x

  const int t     = threadIdx.x;
  const int c     = t & 31;
  const int eh    = (t >> 5) & 1;
  const int bq    = t >> 6;
  const int xcd   = blockIdx.x & 7;
  const int sl    = blockIdx.x >> 3;  // 0..95
  const int ic    = xcd * ICX + (sl >> 3);
  const int bslab = sl & 7;
  const int b0    = bslab * BC_;
  const int i0    = ic * ICt;

  int fsrc[4];
#pragma unroll
  for (int k = 0; k < 4; ++k) {
    int cc = (t >> 5) + 8*k;
    fsrc[k] = cc*32 + ((c - cc) & 31);
  }

  // stage x f32 (192 float4: 8 b x 24)
  if (t < BC_*ICt*2) {
    int b = t / (ICt*2), r = t % (ICt*2);
    xl[t] = ((const float4*)x)[ ((size_t)(b0 + b)*I_ + i0)*2 + r ];
  }

  const float4* wg = (const float4*)(W + (size_t)i0 * (C_*D_*E_));
#pragma unroll
  for (int k = 0; k < 4; ++k) gload_lds16(wg + fsrc[k],          &Wl[0][t + 256*k]);
#pragma unroll
  for (int k = 0; k < 4; ++k) gload_lds16(wg + WROW4 + fsrc[k],  &Wl[1][t + 256*k]);

  float acc[2][8];
#pragma unroll
  for (int j = 0; j < 2; ++j)
#pragma unroll
    for (int e = 0; e < 8; ++e) acc[j][e] = 0.f;

  int cur = 0;
  for (int ii = 0; ii < ICt; ++ii) {
    WAITLG0();
    __builtin_amdgcn_s_barrier();
    __builtin_amdgcn_sched_barrier(0);

    if (ii + 2 < ICt) {
      int pre = cur + 2; if (pre >= 3) pre -= 3;
      const float4* wn = wg + (size_t)(ii + 2) * WROW4;
#pragma unroll
      for (int k = 0; k < 4; ++k)
        gload_lds16(wn + fsrc[k], &Wl[pre][t + 256*k]);
    }

    if (ii < ICt - 2)       WAITVM8();
    else if (ii == ICt - 2) WAITVM4();
    else                    WAITVM0();
    __builtin_amdgcn_s_barrier();
    __builtin_amdgcn_sched_barrier(0);

    __builtin_amdgcn_s_setprio(1);
    float xv[2][8];
#pragma unroll
    for (int j = 0; j < 2; ++j) {
      float4 a = xl[(bq*2 + j)*(ICt*2) + ii*2 + 0];
      float4 b = xl[(bq*2 + j)*(ICt*2) + ii*2 + 1];
      xv[j][0]=a.x; xv[j][1]=a.y; xv[j][2]=a.z; xv[j][3]=a.w;
      xv[j][4]=b.x; xv[j][5]=b.y; xv[j][6]=b.z; xv[j][7]=b.w;
    }

    float uh[2][8];
#pragma unroll
    for (int j = 0; j < 2; ++j)
#pragma unroll
      for (int e = 0; e < 8; ++e) uh[j][e] = 0.f;

#pragma unroll
    for (int d = 0; d < D_; ++d) {
#pragma unroll
      for (int qq = 0; qq < 2; ++qq) {
        float4 wv = Wl[cur][c*32 + (((d*4 + eh*2 + qq) + c) & 31)];
        const int eb = qq*4;
#pragma unroll
        for (int j = 0; j < 2; ++j) {
          uh[j][eb+0] = fmaf(xv[j][d], wv.x, uh[j][eb+0]);
          uh[j][eb+1] = fmaf(xv[j][d], wv.y, uh[j][eb+1]);
          uh[j][eb+2] = fmaf(xv[j][d], wv.z, uh[j][eb+2]);
          uh[j][eb+3] = fmaf(xv[j][d], wv.w, uh[j][eb+3]);
        }
      }
    }

#pragma unroll
    for (int j = 0; j < 2; ++j)
#pragma unroll
      for (int e = 0; e < 8; ++e) acc[j][e] = fmaf((1.0f/C_), uh[j][e], acc[j][e]);
    __builtin_amdgcn_s_setprio(0);

    cur = (cur + 1 == 3) ? 0 : cur + 1;
  }

  // partial s (f16): [NIC][B][C][E], 16B store per j  (reduce0 critical path)
#pragma unroll
  for (int j = 0; j < 2; ++j) {
    size_t base = ((size_t)ic * B_ + (b0 + bq*2 + j)) * (C_*E_) + (size_t)c*E_ + eh*8;
    float4 o;
    o.x = h2bits(acc[j][0], acc[j][1]);
    o.y = h2bits(acc[j][2], acc[j][3]);
    o.z = h2bits(acc[j][4], acc[j][5]);
    o.w = h2bits(acc[j][6], acc[j][7]);
    *(float4*)(partial + base) = o;
  }

  // ---- epilogue converts (off reduce0's critical path) ----
  // W -> f16 granules [i][c][q=d*2+eh][8 halfs]; this block does ii with
  // (ii&7)==bslab (exactly-once grid-wide); source L2-hot from our own DMA.
  for (int ii = bslab; ii < ICt; ii += 8) {
    const int i = i0 + ii;
    const float4* src = (const float4*)(W + (size_t)i * (C_*D_*E_));
#pragma unroll
    for (int g = 0; g < 2; ++g) {
      int G  = t*2 + g;                 // granule 0..511
      int cc = G >> 4, q = G & 15;
      int d  = q >> 1, eo = q & 1;
      const float4* s4 = src + (cc*8 + d)*4 + eo*2;
      float4 a = s4[0], b = s4[1];
      float4 o;
      o.x = h2bits(a.x, a.y); o.y = h2bits(a.z, a.w);
      o.z = h2bits(b.x, b.y); o.w = h2bits(b.z, b.w);
      *(float4*)(Wh + (size_t)i * 4096 + G*8) = o;
    }
  }
  // x -> duplicated half2 xh[b][i][d] from staged LDS (disjoint per block)
  if (t < BC_*ICt*2) {
    int b = t / (ICt*2), r = t % (ICt*2);
    float4 a = xl[t];
    float4 o;
    o.x = h2bits(a.x, a.x); o.y = h2bits(a.y, a.y);
    o.z = h2bits(a.z, a.z); o.w = h2bits(a.w, a.w);
    size_t idx = ((size_t)(b0 + b)*I_ + (i0 + (r >> 1)))*D_ + (r & 1)*4;
    *(float4*)(xh + idx) = o;
  }
}

// ---------------- Passes 1,2: packed-f16 (r12 structure + setprio) ---------
// PER=2 periods, 3 x 16KB 2-i buffers, 2-period-deep counted vmcnt (ladder
// 8/4/0), granule swizzle q^(cc&15) on global source, broadcast b128 x reads.
template<int MODE>   // unused template kept minimal: ROUTE always true here
__global__ __launch_bounds__(256)
void caps_pass_f16(const __half2* __restrict__ xh, const char* __restrict__ Wh,
                   const float* __restrict__ vacc, __half* __restrict__ partial)
{
  __shared__ float4 Wl[3][1024];      // 3 x 16KB buffers (2 W-i's each)
  __shared__ __half2 xl[BC_*ICt*D_];  // 768 half2 (3KB)

  const int t   = threadIdx.x;
  const int c   = t & 31;
  const int eh  = (t >> 5) & 1;
  const int bq  = t >> 6;
  const int xcd = blockIdx.x & 7;
  const int sl  = blockIdx.x >> 3;    // 0..95
  const int ic  = xcd * ICX + (sl >> 3);
  const int b0  = (sl & 7) * BC_;
  const int i0  = ic * ICt;

  int fsrc[2];
#pragma unroll
  for (int k = 0; k < 2; ++k) {
    int g = t + 256*k, cc = g >> 4, q = g & 15;
    fsrc[k] = cc*256 + ((q ^ (cc & 15)) << 4);    // byte offset in Wh[i]
  }

  __half2 vrp[2][4];
#pragma unroll
  for (int j = 0; j < 2; ++j) {
    const float4* vp = (const float4*)(vacc + (((size_t)(b0 + bq*2 + j)*C_ + c)*E_ + eh*8));
    float4 a = vp[0], b = vp[1];
    vrp[j][0] = __float22half2_rn({a.x, a.y});
    vrp[j][1] = __float22half2_rn({a.z, a.w});
    vrp[j][2] = __float22half2_rn({b.x, b.y});
    vrp[j][3] = __float22half2_rn({b.z, b.w});
  }

  if (t < BC_*ICt*D_/4) {
    int b = t / 24, r = t % 24;
    float4 v = ((const float4*)(xh + ((size_t)(b0 + b)*I_ + i0)*D_))[r];
    ((float4*)xl)[b*24 + r] = v;
  }

  const char* wg = Wh + (size_t)i0 * WIB;
#pragma unroll
  for (int k = 0; k < 4; ++k)
    gload_lds16(wg + (k>>1)*WIB + fsrc[k&1], (char*)&Wl[0][0] + (t + 256*k)*16);
#pragma unroll
  for (int k = 0; k < 4; ++k)
    gload_lds16(wg + WIB*2 + (k>>1)*WIB + fsrc[k&1], (char*)&Wl[1][0] + (t + 256*k)*16);

  __half2 accp[2][4];
#pragma unroll
  for (int j = 0; j < 2; ++j)
#pragma unroll
    for (int q = 0; q < 4; ++q) accp[j][q] = __half2{__half(0.f), __half(0.f)};

  int cur = 0;
  for (int p = 0; p < ICt/2; ++p) {
    WAITLG0();
    __builtin_amdgcn_s_barrier();
    __builtin_amdgcn_sched_barrier(0);

    if (p + 2 < ICt/2) {
      int pre = cur + 2; if (pre >= 3) pre -= 3;
      const char* wn = wg + (size_t)(p + 2) * (2*WIB);
#pragma unroll
      for (int k = 0; k < 4; ++k)
        gload_lds16(wn + (k>>1)*WIB + fsrc[k&1], (char*)&Wl[pre][0] + (t + 256*k)*16);
    }

    if (p < ICt/2 - 2)       WAITVM8();
    else if (p == ICt/2 - 2) WAITVM4();
    else                     WAITVM0();
    __builtin_amdgcn_s_barrier();
    __builtin_amdgcn_sched_barrier(0);

    __builtin_amdgcn_s_setprio(1);
#pragma unroll
    for (int il = 0; il < 2; ++il) {
      const int ii = p*2 + il;

      __half2 xd0[8], xd1[8];
      {
        const float4* xr = (const float4*)xl;
        float4 a0 = xr[((bq*2 + 0)*ICt + ii)*2 + 0];
        float4 b0v = xr[((bq*2 + 0)*ICt + ii)*2 + 1];
        float4 a1 = xr[((bq*2 + 1)*ICt + ii)*2 + 0];
        float4 b1v = xr[((bq*2 + 1)*ICt + ii)*2 + 1];
        xd0[0]=__builtin_bit_cast(__half2,a0.x); xd0[1]=__builtin_bit_cast(__half2,a0.y);
        xd0[2]=__builtin_bit_cast(__half2,a0.z); xd0[3]=__builtin_bit_cast(__half2,a0.w);
        xd0[4]=__builtin_bit_cast(__half2,b0v.x); xd0[5]=__builtin_bit_cast(__half2,b0v.y);
        xd0[6]=__builtin_bit_cast(__half2,b0v.z); xd0[7]=__builtin_bit_cast(__half2,b0v.w);
        xd1[0]=__builtin_bit_cast(__half2,a1.x); xd1[1]=__builtin_bit_cast(__half2,a1.y);
        xd1[2]=__builtin_bit_cast(__half2,a1.z); xd1[3]=__builtin_bit_cast(__half2,a1.w);
        xd1[4]=__builtin_bit_cast(__half2,b1v.x); xd1[5]=__builtin_bit_cast(__half2,b1v.y);
        xd1[6]=__builtin_bit_cast(__half2,b1v.z); xd1[7]=__builtin_bit_cast(__half2,b1v.w);
      }

      __half2 uhp[2][4];
#pragma unroll
      for (int j = 0; j < 2; ++j)
#pragma unroll
        for (int q = 0; q < 4; ++q) uhp[j][q] = __half2{__half(0.f), __half(0.f)};

      const char* wrow = (const char*)&Wl[cur][0] + il*WIB + c*256;
#pragma unroll
      for (int d = 0; d < D_; ++d) {
        float4 w4 = *(const float4*)(wrow + ((((d*2 + eh) ^ (c & 15))) << 4));
        __half2 w0 = __builtin_bit_cast(__half2, w4.x);
        __half2 w1 = __builtin_bit_cast(__half2, w4.y);
        __half2 w2 = __builtin_bit_cast(__half2, w4.z);
        __half2 w3 = __builtin_bit_cast(__half2, w4.w);
        uhp[0][0] = __hfma2(xd0[d], w0, uhp[0][0]);
        uhp[0][1] = __hfma2(xd0[d], w1, uhp[0][1]);
        uhp[0][2] = __hfma2(xd0[d], w2, uhp[0][2]);
        uhp[0][3] = __hfma2(xd0[d], w3, uhp[0][3]);
        uhp[1][0] = __hfma2(xd1[d], w0, uhp[1][0]);
        uhp[1][1] = __hfma2(xd1[d], w1, uhp[1][1]);
        uhp[1][2] = __hfma2(xd1[d], w2, uhp[1][2]);
        uhp[1][3] = __hfma2(xd1[d], w3, uhp[1][3]);
      }

      float coef[2];
#pragma unroll
      for (int j = 0; j < 2; ++j) {
        float lg = 0.f;
#pragma unroll
        for (int q = 0; q < 4; ++q) lg = dot2f(uhp[j][q], vrp[j][q], lg);
        lg += __shfl_xor(lg, 32, 64);          // combine e-halves
        float pexp = __expf(lg);               // no max-sub: |lg| bounded
        float s = pexp;
#pragma unroll
        for (int mk = 16; mk >= 1; mk >>= 1) s += __shfl_xor(s, mk, 64);
        coef[j] = pexp * __builtin_amdgcn_rcpf(s);
      }

#pragma unroll
      for (int j = 0; j < 2; ++j) {
        __half2 cp = __float2half2_rn(coef[j]);
#pragma unroll
        for (int q = 0; q < 4; ++q) accp[j][q] = __hfma2(cp, uhp[j][q], accp[j][q]);
      }
    }
    __builtin_amdgcn_s_setprio(0);

    cur = (cur + 1 == 3) ? 0 : cur + 1;
  }

#pragma unroll
  for (int j = 0; j < 2; ++j) {
    size_t base = ((size_t)ic * B_ + (b0 + bq*2 + j)) * (C_*E_) + (size_t)c*E_ + eh*8;
    float4 o;
    o.x = __builtin_bit_cast(float, accp[j][0]);
    o.y = __builtin_bit_cast(float, accp[j][1]);
    o.z = __builtin_bit_cast(float, accp[j][2]);
    o.w = __builtin_bit_cast(float, accp[j][3]);
    *(float4*)(partial + base) = o;
  }
}

// Fused reduce+squash on f16 partial: 512 blocks x 256 thr (2 blocks/CU).
// thread (pair = bid*32 + (t&31), part = t>>5) sums 12 chunks; LDS combine of
// 8 parts; squash over e. mode 0: vacc = v ; 1: vacc += v ; 2: out = v
__global__ __launch_bounds__(256)
void reduce_squash(const __half2* __restrict__ partial, float* __restrict__ vacc,
                   float* __restrict__ out, int mode)
{
  __shared__ float2 sm[256];
  const int t    = threadIdx.x;
  const int pair = blockIdx.x*32 + (t & 31);
  const int part = t >> 5;
  const __half2* p = partial + (size_t)(part*(NIC/8)) * SCE2 + pair;
  float2 s = {0.f, 0.f};
#pragma unroll
  for (int k = 0; k < NIC/8; ++k) {
    float2 f = __half22float2(p[(size_t)k * SCE2]);
    s.x += f.x; s.y += f.y;
  }
  sm[t] = s;
  __syncthreads();
  if (t < 32) {
    float2 tot = {0.f, 0.f};
#pragma unroll
    for (int pp = 0; pp < 8; ++pp) {
      float2 v = sm[t + 32*pp];
      tot.x += v.x; tot.y += v.y;
    }
    float sq = tot.x*tot.x + tot.y*tot.y;
    sq += __shfl_xor(sq, 1); sq += __shfl_xor(sq, 2); sq += __shfl_xor(sq, 4);
    float scale = sq / (1.f + sq) / (sqrtf(sq) + 1e-8f);
    float vx = scale * tot.x, vy = scale * tot.y;
    const int cell = pair * 2;
    if (mode == 0)      { vacc[cell] = vx;  vacc[cell+1] = vy;  }
    else if (mode == 1) { vacc[cell] += vx; vacc[cell+1] += vy; }
    else                { out[cell]  = vx;  out[cell+1]  = vy;  }
  }
}

extern "C" void kernel_launch(void* const* d_in, const int* in_sizes, int n_in,
                              void* d_out, int out_size, void* d_ws, size_t ws_size,
                              hipStream_t stream)
{
  const float* x = (const float*)d_in[0];
  const float* W = (const float*)d_in[1];
  float* out     = (float*)d_out;

  char* ws = (char*)d_ws;
  __half*  partial = (__half*)ws;                    ws += (size_t)NIC*SCE*2;     // 6.3 MB
  float*   vacc    = (float*)ws;                     ws += (size_t)SCE*4;         // 128 KB
  __half*  Wh      = (__half*)ws;                    ws += (size_t)I_*C_*D_*E_*2; // 9.4 MB
  __half2* xh      = (__half2*)ws;                                               // 2.36 MB

  dim3 pg(NIC * (B_/BC_));                           // 768 blocks (3/CU exact)
  const int rg = SCE2 / 32;                          // 512 blocks

  // iter 0 (f32) + fused W/x -> f16 conversion
  caps_pass0<<<pg, 256, 0, stream>>>(x, W, partial, Wh, xh);
  reduce_squash<<<rg, 256, 0, stream>>>((const __half2*)partial, vacc, nullptr, 0);
  // iter 1: logits = u_hat . v0
  caps_pass_f16<0><<<pg, 256, 0, stream>>>(xh, (const char*)Wh, vacc, partial);
  reduce_squash<<<rg, 256, 0, stream>>>((const __half2*)partial, vacc, nullptr, 1);
  // iter 2: logits = u_hat . (v0+v1)
  caps_pass_f16<1><<<pg, 256, 0, stream>>>(xh, (const char*)Wh, vacc, partial);
  reduce_squash<<<rg, 256, 0, stream>>>((const __half2*)partial, vacc, out, 2);
}